// Round 1
// baseline (167.213 us; speedup 1.0000x reference)
//
#include <hip/hip_runtime.h>
#include <stdint.h>

#define EPSV 1e-5f

typedef __attribute__((ext_vector_type(4))) float f32x4;
typedef __attribute__((ext_vector_type(8))) short bf16x8;

__device__ __forceinline__ unsigned short f2bf(float x){
  union{float f; uint32_t u;} a; a.f=x;
  uint32_t r = a.u + 0x7fffu + ((a.u>>16)&1u);
  return (unsigned short)(r>>16);
}
// split float into bf16 hi (truncated) + bf16 lo (RNE of remainder); x ~= hi+lo with ~2^-17 rel err
__device__ __forceinline__ void split2(float x, unsigned short& h, unsigned short& l){
  union{float f; uint32_t u;} a; a.f=x;
  union{uint32_t u; float f;} b; b.u = a.u & 0xffff0000u;
  h = (unsigned short)(b.u>>16);
  l = f2bf(x - b.f);
}
__device__ __forceinline__ f32x4 mfma16(bf16x8 a, bf16x8 b, f32x4 c){
  return __builtin_amdgcn_mfma_f32_16x16x32_bf16(a, b, c, 0, 0, 0);
}

// ---------------- GEMM + BN:  Out[b][o][n] = BN(sum_c W[o][c] * X[b][c][n]) ----------------
// K = 256 fixed, N = 4096 fixed, M passed (768 or 256). Split-bf16 3-term MFMA (~fp32 accuracy).
__global__ __launch_bounds__(256)
void gemm_bn_kernel(const float* __restrict__ W, const float* __restrict__ X,
                    float* __restrict__ Out,
                    const float* __restrict__ gg, const float* __restrict__ bb,
                    const float* __restrict__ bm, const float* __restrict__ bv,
                    int M)
{
  const int t = threadIdx.x;
  const int lane = t & 63, wid = t >> 6;
  const int nblk = blockIdx.x;   // 0..31
  const int mblk = blockIdx.y;   // 0..M/128-1
  const int b    = blockIdx.z;   // 0..1
  const int N = 4096, K = 256;

  __shared__ __align__(16) unsigned short Ah[128][40], Al[128][40];
  __shared__ __align__(16) unsigned short Bh[128][40], Bl[128][40];
  __shared__ float scale_s[128], shift_s[128];

  if (t < 128){
    int o = mblk*128 + t;
    float s = gg[o]*rsqrtf(bv[o] + EPSV);
    scale_s[t] = s;
    shift_s[t] = bb[o] - bm[o]*s;
  }
  __syncthreads();

  const float* Xb = X + (size_t)b*K*N;

  f32x4 acc[4][4];
  #pragma unroll
  for (int i=0;i<4;i++)
    #pragma unroll
    for (int j=0;j<4;j++){ f32x4 z = {0.f,0.f,0.f,0.f}; acc[i][j] = z; }

  const int wr = (wid>>1)*64, wc = (wid&1)*64;

  for (int ks = 0; ks < 8; ++ks){
    // stage A tile [128 o][32 c], BN scale folded, hi/lo split
    #pragma unroll
    for (int i=0;i<4;i++){
      int idx = t + i*256;          // 0..1023
      int row = idx >> 3;           // 8 float4 per row
      int c4  = idx & 7;
      const float* wp = W + (size_t)(mblk*128+row)*K + ks*32 + c4*4;
      f32x4 v = *(const f32x4*)wp;
      float s = scale_s[row];
      #pragma unroll
      for (int j=0;j<4;j++){
        unsigned short hh, ll; split2(v[j]*s, hh, ll);
        Ah[row][c4*4+j]=hh; Al[row][c4*4+j]=ll;
      }
    }
    // stage B tile transposed: X[c][n] -> Bs[n][c]
    #pragma unroll
    for (int i=0;i<4;i++){
      int idx = t + i*256;
      int crow = idx >> 5;          // 32 float4 per c-row
      int n4 = idx & 31;
      const float* xp = Xb + (size_t)(ks*32 + crow)*N + nblk*128 + n4*4;
      f32x4 v = *(const f32x4*)xp;
      #pragma unroll
      for (int j=0;j<4;j++){
        unsigned short hh, ll; split2(v[j], hh, ll);
        Bh[n4*4+j][crow]=hh; Bl[n4*4+j][crow]=ll;
      }
    }
    __syncthreads();

    bf16x8 ah[4], al[4], bh[4], bl[4];
    #pragma unroll
    for (int i=0;i<4;i++){
      ah[i] = *(const bf16x8*)&Ah[wr + i*16 + (lane&15)][(lane>>4)*8];
      al[i] = *(const bf16x8*)&Al[wr + i*16 + (lane&15)][(lane>>4)*8];
      bh[i] = *(const bf16x8*)&Bh[wc + i*16 + (lane&15)][(lane>>4)*8];
      bl[i] = *(const bf16x8*)&Bl[wc + i*16 + (lane&15)][(lane>>4)*8];
    }
    #pragma unroll
    for (int i=0;i<4;i++)
      #pragma unroll
      for (int j=0;j<4;j++){
        acc[i][j] = mfma16(ah[i], bh[j], acc[i][j]);
        acc[i][j] = mfma16(al[i], bh[j], acc[i][j]);
        acc[i][j] = mfma16(ah[i], bl[j], acc[i][j]);
      }
    __syncthreads();
  }

  // epilogue: + shift, store fp32
  #pragma unroll
  for (int i=0;i<4;i++)
    #pragma unroll
    for (int j=0;j<4;j++){
      int lrow0 = wr + i*16 + ((lane>>4)<<2);
      int ocol  = nblk*128 + wc + j*16 + (lane&15);
      float* op = Out + ((size_t)b*M + (size_t)(mblk*128 + lrow0))*N + ocol;
      #pragma unroll
      for (int r=0;r<4;r++)
        op[(size_t)r*N] = acc[i][j][r] + shift_s[lrow0 + r];
    }
}

// ---------------- Flash attention per (ba, h, 128-row query block) ----------------
// qkv layout: [b][768][4096]; channel o = h*96 + {0..31:q, 32..63:k, 64..95:v}; n = area*1024 + na
// writes obuf[b][h*32+d][n] = attention output (channel-major, ready for proj GEMM)
__global__ __launch_bounds__(256)
void attn_kernel(const float* __restrict__ qkv, float* __restrict__ obuf)
{
  const int t = threadIdx.x, lane = t & 63, wid = t >> 6;
  const int nblk = blockIdx.x;   // 0..7
  const int h    = blockIdx.y;   // 0..7
  const int ba   = blockIdx.z;   // 0..7
  const int b = ba >> 2, area = ba & 3;
  const int N = 4096;

  const float* qbase = qkv + ((size_t)b*768 + h*96) * N + area*1024;
  const float* kbase = qbase + (size_t)32*N;
  const float* vbase = qbase + (size_t)64*N;

  __shared__ __align__(16) unsigned short Qh[128][40], Ql[128][40];  // [n][d]
  __shared__ __align__(16) unsigned short Kh[64][40],  Kl[64][40];   // [m][d]
  __shared__ __align__(16) unsigned short Vh[32][72],  Vl[32][72];   // [d][m]
  __shared__ __align__(16) unsigned short Pl[4][32][72];             // per-wave [n][m]
  __shared__ float rsc[4][32];
  __shared__ float rinv[4][32];

  const int n0 = nblk*128;

  // stage Q (transposed, scaled by hd^-0.5, hi/lo)
  #pragma unroll
  for (int i=0;i<4;i++){
    int idx = t + i*256;            // 0..1023
    int d  = idx >> 5;              // 32 float4 per d-row
    int n4 = idx & 31;
    f32x4 v = *(const f32x4*)(qbase + (size_t)d*N + n0 + n4*4);
    #pragma unroll
    for (int j=0;j<4;j++){
      unsigned short hh,ll; split2(v[j]*0.17677669529663687f, hh, ll);
      Qh[n4*4+j][d]=hh; Ql[n4*4+j][d]=ll;
    }
  }
  __syncthreads();

  bf16x8 qh[2], ql[2];
  #pragma unroll
  for (int i=0;i<2;i++){
    qh[i] = *(const bf16x8*)&Qh[wid*32 + i*16 + (lane&15)][(lane>>4)*8];
    ql[i] = *(const bf16x8*)&Ql[wid*32 + i*16 + (lane&15)][(lane>>4)*8];
  }

  float mrun[2][4], srun[2][4];
  #pragma unroll
  for (int i=0;i<2;i++)
    #pragma unroll
    for (int r=0;r<4;r++){ mrun[i][r] = -1e30f; srun[i][r] = 0.f; }
  f32x4 oacc[2][2];
  #pragma unroll
  for (int i=0;i<2;i++)
    #pragma unroll
    for (int j=0;j<2;j++){ f32x4 z = {0.f,0.f,0.f,0.f}; oacc[i][j] = z; }

  for (int m0 = 0; m0 < 1024; m0 += 64){
    // stage K (transposed hi/lo) and V (natural [d][m] hi/lo)
    #pragma unroll
    for (int i=0;i<2;i++){
      int idx = t + i*256;          // 0..511
      int d  = idx >> 4;            // 16 float4 per d-row (64 m)
      int m4 = idx & 15;
      f32x4 kv = *(const f32x4*)(kbase + (size_t)d*N + m0 + m4*4);
      #pragma unroll
      for (int j=0;j<4;j++){
        unsigned short hh,ll; split2(kv[j], hh, ll);
        Kh[m4*4+j][d]=hh; Kl[m4*4+j][d]=ll;
      }
      f32x4 vv = *(const f32x4*)(vbase + (size_t)d*N + m0 + m4*4);
      #pragma unroll
      for (int j=0;j<4;j++){
        unsigned short hh,ll; split2(vv[j], hh, ll);
        Vh[d][m4*4+j]=hh; Vl[d][m4*4+j]=ll;
      }
    }
    __syncthreads();

    // S = Q^T K (3-term split)
    bf16x8 kfh[4], kfl[4];
    #pragma unroll
    for (int j=0;j<4;j++){
      kfh[j] = *(const bf16x8*)&Kh[j*16 + (lane&15)][(lane>>4)*8];
      kfl[j] = *(const bf16x8*)&Kl[j*16 + (lane&15)][(lane>>4)*8];
    }
    f32x4 s[2][4];
    #pragma unroll
    for (int i=0;i<2;i++)
      #pragma unroll
      for (int j=0;j<4;j++){
        f32x4 z = {0.f,0.f,0.f,0.f};
        z = mfma16(qh[i], kfh[j], z);
        z = mfma16(ql[i], kfh[j], z);
        z = mfma16(qh[i], kfl[j], z);
        s[i][j] = z;
      }

    // online softmax; write P (bf16) + per-row rescale factor
    #pragma unroll
    for (int i=0;i<2;i++){
      float corr[4];
      #pragma unroll
      for (int r=0;r<4;r++){
        float mx = fmaxf(fmaxf(s[i][0][r], s[i][1][r]), fmaxf(s[i][2][r], s[i][3][r]));
        #pragma unroll
        for (int msk=1; msk<16; msk<<=1) mx = fmaxf(mx, __shfl_xor(mx, msk, 64));
        float mn = fmaxf(mrun[i][r], mx);
        corr[r] = __expf(mrun[i][r] - mn);
        mrun[i][r] = mn;
      }
      #pragma unroll
      for (int r=0;r<4;r++){
        float acc = 0.f;
        int nrow = i*16 + ((lane>>4)<<2) + r;
        #pragma unroll
        for (int j=0;j<4;j++){
          float p = __expf(s[i][j][r] - mrun[i][r]);
          Pl[wid][nrow][j*16 + (lane&15)] = f2bf(p);
          acc += p;
        }
        #pragma unroll
        for (int msk=1; msk<16; msk<<=1) acc += __shfl_xor(acc, msk, 64);
        srun[i][r] = srun[i][r]*corr[r] + acc;
        if ((lane&15)==0) rsc[wid][nrow] = corr[r];
      }
    }
    __syncthreads();

    // rescale O^T and accumulate O^T += V * P^T  (V split hi/lo)
    #pragma unroll
    for (int nt=0;nt<2;nt++){
      float c = rsc[wid][nt*16 + (lane&15)];
      #pragma unroll
      for (int dt=0;dt<2;dt++)
        #pragma unroll
        for (int r=0;r<4;r++) oacc[dt][nt][r] *= c;
    }
    #pragma unroll
    for (int ksd=0;ksd<2;ksd++){
      bf16x8 vfh[2], vfl[2], pf[2];
      #pragma unroll
      for (int dt=0;dt<2;dt++){
        vfh[dt] = *(const bf16x8*)&Vh[dt*16 + (lane&15)][ksd*32 + (lane>>4)*8];
        vfl[dt] = *(const bf16x8*)&Vl[dt*16 + (lane&15)][ksd*32 + (lane>>4)*8];
      }
      #pragma unroll
      for (int nt=0;nt<2;nt++)
        pf[nt] = *(const bf16x8*)&Pl[wid][nt*16 + (lane&15)][ksd*32 + (lane>>4)*8];
      #pragma unroll
      for (int dt=0;dt<2;dt++)
        #pragma unroll
        for (int nt=0;nt<2;nt++){
          oacc[dt][nt] = mfma16(vfh[dt], pf[nt], oacc[dt][nt]);
          oacc[dt][nt] = mfma16(vfl[dt], pf[nt], oacc[dt][nt]);
        }
    }
    __syncthreads();
  }

  // finalize: divide by row sums, write O^T to obuf[b][h*32+d][n]
  if ((lane&15)==0){
    #pragma unroll
    for (int i=0;i<2;i++)
      #pragma unroll
      for (int r=0;r<4;r++)
        rinv[wid][i*16 + ((lane>>4)<<2) + r] = 1.0f / srun[i][r];
  }
  __syncthreads();
  const int c0 = h*32;
  const int ng = area*1024 + n0 + wid*32;
  #pragma unroll
  for (int dt=0;dt<2;dt++)
    #pragma unroll
    for (int nt=0;nt<2;nt++){
      float inv = rinv[wid][nt*16 + (lane&15)];
      int d = c0 + dt*16 + ((lane>>4)<<2);
      size_t base = ((size_t)b*256 + d)*(size_t)N + (size_t)(ng + nt*16 + (lane&15));
      #pragma unroll
      for (int r=0;r<4;r++)
        obuf[base + (size_t)r*N] = oacc[dt][nt][r]*inv;
    }
}

// ---------------- depthwise 7x7 conv + BN, accumulate into obuf ----------------
__global__ __launch_bounds__(256)
void dwconv_bn_add(const float* __restrict__ qkv, const float* __restrict__ wpe,
                   const float* __restrict__ gg, const float* __restrict__ bb,
                   const float* __restrict__ bm, const float* __restrict__ bv,
                   float* __restrict__ obuf)
{
  const int t = threadIdx.x;
  const int c = blockIdx.x;      // 0..255
  const int b = blockIdx.y;      // 0..1
  const float* src = qkv + ((size_t)b*768 + (size_t)((c>>5)*96 + 64 + (c&31)))*4096;
  __shared__ float tile[70*70];
  for (int idx = t; idx < 4900; idx += 256){
    int y = idx/70 - 3, x = idx%70 - 3;
    float v = 0.f;
    if ((unsigned)y < 64u && (unsigned)x < 64u) v = src[y*64 + x];
    tile[idx] = v;
  }
  float wreg[49];
  #pragma unroll
  for (int i=0;i<49;i++) wreg[i] = wpe[c*49 + i];
  float sc = gg[c]*rsqrtf(bv[c]+EPSV);
  float sh = bb[c] - bm[c]*sc;
  __syncthreads();
  float* dst = obuf + ((size_t)b*256 + c)*4096;
  #pragma unroll
  for (int p=0;p<16;p++){
    int pix = t + p*256;
    int y = pix >> 6, x = pix & 63;
    float acc = 0.f;
    #pragma unroll
    for (int ky=0;ky<7;ky++)
      #pragma unroll
      for (int kx=0;kx<7;kx++)
        acc += tile[(y+ky)*70 + x + kx] * wreg[ky*7+kx];
    dst[pix] += acc*sc + sh;
  }
}

extern "C" void kernel_launch(void* const* d_in, const int* in_sizes, int n_in,
                              void* d_out, int out_size, void* d_ws, size_t ws_size,
                              hipStream_t stream) {
  const float* x       = (const float*)d_in[0];
  const float* w_qkv   = (const float*)d_in[1];
  const float* g_qkv   = (const float*)d_in[2];
  const float* b_qkv   = (const float*)d_in[3];
  const float* m_qkv   = (const float*)d_in[4];
  const float* var_qkv = (const float*)d_in[5];
  const float* w_pe    = (const float*)d_in[6];
  const float* g_pe    = (const float*)d_in[7];
  const float* b_pe    = (const float*)d_in[8];
  const float* m_pe    = (const float*)d_in[9];
  const float* var_pe  = (const float*)d_in[10];
  const float* w_proj  = (const float*)d_in[11];
  const float* g_proj  = (const float*)d_in[12];
  const float* b_proj  = (const float*)d_in[13];
  const float* m_proj  = (const float*)d_in[14];
  const float* var_proj= (const float*)d_in[15];

  float* qkv  = (float*)d_ws;                                  // 2*768*4096 f32 = 24 MiB
  float* obuf = (float*)((char*)d_ws + (size_t)2*768*4096*4);  // 2*256*4096 f32 = 8 MiB
  float* out  = (float*)d_out;

  gemm_bn_kernel<<<dim3(32,6,2), 256, 0, stream>>>(w_qkv, x, qkv,
      g_qkv, b_qkv, m_qkv, var_qkv, 768);
  attn_kernel<<<dim3(8,8,8), 256, 0, stream>>>(qkv, obuf);
  dwconv_bn_add<<<dim3(256,2), 256, 0, stream>>>(qkv, w_pe,
      g_pe, b_pe, m_pe, var_pe, obuf);
  gemm_bn_kernel<<<dim3(32,2,2), 256, 0, stream>>>(w_proj, obuf, out,
      g_proj, b_proj, m_proj, var_proj, 256);
}

// Round 2
// 151.460 us; speedup vs baseline: 1.1040x; 1.1040x over previous
//
#include <hip/hip_runtime.h>
#include <stdint.h>

#define EPSV 1e-5f

typedef __attribute__((ext_vector_type(4))) float f32x4;
typedef __attribute__((ext_vector_type(8))) short bf16x8;

__device__ __forceinline__ unsigned short f2bf(float x){
  union{float f; uint32_t u;} a; a.f=x;
  uint32_t r = a.u + 0x7fffu + ((a.u>>16)&1u);
  return (unsigned short)(r>>16);
}
__device__ __forceinline__ float bf2f(unsigned short u){
  union{uint32_t x; float f;} a; a.x = (uint32_t)u<<16; return a.f;
}
// split float into bf16 hi (truncated) + bf16 lo (RNE of remainder)
__device__ __forceinline__ void split2(float x, unsigned short& h, unsigned short& l){
  union{float f; uint32_t u;} a; a.f=x;
  union{uint32_t u; float f;} b; b.u = a.u & 0xffff0000u;
  h = (unsigned short)(b.u>>16);
  l = f2bf(x - b.f);
}
__device__ __forceinline__ f32x4 mfma16(bf16x8 a, bf16x8 b, f32x4 c){
  return __builtin_amdgcn_mfma_f32_16x16x32_bf16(a, b, c, 0, 0, 0);
}
__device__ __forceinline__ f32x4 vmax4(f32x4 a, f32x4 b){
  f32x4 r; r[0]=fmaxf(a[0],b[0]); r[1]=fmaxf(a[1],b[1]);
  r[2]=fmaxf(a[2],b[2]); r[3]=fmaxf(a[3],b[3]); return r;
}
// unpack 8 consecutive packed u32 (hi<<16|lo) into hi/lo bf16x8
__device__ __forceinline__ void unpack8(const uint4& a, const uint4& b, bf16x8& hi, bf16x8& lo){
  union { uint32_t w[4]; bf16x8 v; } H, L;
  H.w[0] = __builtin_amdgcn_perm(a.y, a.x, 0x07060302u);
  H.w[1] = __builtin_amdgcn_perm(a.w, a.z, 0x07060302u);
  H.w[2] = __builtin_amdgcn_perm(b.y, b.x, 0x07060302u);
  H.w[3] = __builtin_amdgcn_perm(b.w, b.z, 0x07060302u);
  L.w[0] = __builtin_amdgcn_perm(a.y, a.x, 0x05040100u);
  L.w[1] = __builtin_amdgcn_perm(a.w, a.z, 0x05040100u);
  L.w[2] = __builtin_amdgcn_perm(b.y, b.x, 0x05040100u);
  L.w[3] = __builtin_amdgcn_perm(b.w, b.z, 0x05040100u);
  hi = H.v; lo = L.v;
}

#define QF 0.25503464f   /* 1/sqrt(32) * log2(e) */

// ---------------- GEMM + BN ----------------
// mode 0: Out[b][o][n] = BN(W X) fp32 (proj)
// mode 1: qkv — q/k channels -> qk32 [b*8+h][64][4096] f32 (q pre-scaled by QF);
//               v channels  -> vh/vl bf16 planes [b*8+h][32][4096]
__global__ __launch_bounds__(256)
void gemm_bn_kernel(const float* __restrict__ W, const float* __restrict__ X,
                    float* __restrict__ Out,
                    float* __restrict__ qk32,
                    unsigned short* __restrict__ vhp, unsigned short* __restrict__ vlp,
                    const float* __restrict__ gg, const float* __restrict__ bb,
                    const float* __restrict__ bm, const float* __restrict__ bv,
                    int M, int mode)
{
  const int t = threadIdx.x;
  const int lane = t & 63, wid = t >> 6;
  const int nblk = blockIdx.x;
  const int mblk = blockIdx.y;
  const int b    = blockIdx.z;
  const int N = 4096, K = 256;

  __shared__ __align__(16) unsigned short Ah[128][40], Al[128][40];
  __shared__ __align__(16) unsigned short Bh[128][40], Bl[128][40];
  __shared__ float scale_s[128], shift_s[128];

  if (t < 128){
    int o = mblk*128 + t;
    float s = gg[o]*rsqrtf(bv[o] + EPSV);
    float sh = bb[o] - bm[o]*s;
    if (mode == 1 && (o % 96) < 32){ s *= QF; sh *= QF; }
    scale_s[t] = s;
    shift_s[t] = sh;
  }
  __syncthreads();

  const float* Xb = X + (size_t)b*K*N;

  f32x4 acc[4][4];
  #pragma unroll
  for (int i=0;i<4;i++)
    #pragma unroll
    for (int j=0;j<4;j++){ f32x4 z = {0.f,0.f,0.f,0.f}; acc[i][j] = z; }

  const int wr = (wid>>1)*64, wc = (wid&1)*64;

  for (int ks = 0; ks < 8; ++ks){
    #pragma unroll
    for (int i=0;i<4;i++){
      int idx = t + i*256;
      int row = idx >> 3;
      int c4  = idx & 7;
      const float* wp = W + (size_t)(mblk*128+row)*K + ks*32 + c4*4;
      f32x4 v = *(const f32x4*)wp;
      float s = scale_s[row];
      #pragma unroll
      for (int j=0;j<4;j++){
        unsigned short hh, ll; split2(v[j]*s, hh, ll);
        Ah[row][c4*4+j]=hh; Al[row][c4*4+j]=ll;
      }
    }
    #pragma unroll
    for (int i=0;i<4;i++){
      int idx = t + i*256;
      int crow = idx >> 5;
      int n4 = idx & 31;
      const float* xp = Xb + (size_t)(ks*32 + crow)*N + nblk*128 + n4*4;
      f32x4 v = *(const f32x4*)xp;
      #pragma unroll
      for (int j=0;j<4;j++){
        unsigned short hh, ll; split2(v[j], hh, ll);
        Bh[n4*4+j][crow]=hh; Bl[n4*4+j][crow]=ll;
      }
    }
    __syncthreads();

    bf16x8 ah[4], al[4], bh[4], bl[4];
    #pragma unroll
    for (int i=0;i<4;i++){
      ah[i] = *(const bf16x8*)&Ah[wr + i*16 + (lane&15)][(lane>>4)*8];
      al[i] = *(const bf16x8*)&Al[wr + i*16 + (lane&15)][(lane>>4)*8];
      bh[i] = *(const bf16x8*)&Bh[wc + i*16 + (lane&15)][(lane>>4)*8];
      bl[i] = *(const bf16x8*)&Bl[wc + i*16 + (lane&15)][(lane>>4)*8];
    }
    #pragma unroll
    for (int i=0;i<4;i++)
      #pragma unroll
      for (int j=0;j<4;j++){
        acc[i][j] = mfma16(ah[i], bh[j], acc[i][j]);
        acc[i][j] = mfma16(al[i], bh[j], acc[i][j]);
        acc[i][j] = mfma16(ah[i], bl[j], acc[i][j]);
      }
    __syncthreads();
  }

  if (mode == 0){
    #pragma unroll
    for (int i=0;i<4;i++)
      #pragma unroll
      for (int j=0;j<4;j++){
        int lrow0 = wr + i*16 + ((lane>>4)<<2);
        int ocol  = nblk*128 + wc + j*16 + (lane&15);
        float* op = Out + ((size_t)b*M + (size_t)(mblk*128 + lrow0))*N + ocol;
        #pragma unroll
        for (int r=0;r<4;r++)
          op[(size_t)r*N] = acc[i][j][r] + shift_s[lrow0 + r];
      }
  } else {
    #pragma unroll
    for (int i=0;i<4;i++){
      int base = mblk*128 + wr + i*16;   // multiple of 16; type uniform per i
      int hh = base/96;
      int rem = base - hh*96;
      #pragma unroll
      for (int j=0;j<4;j++){
        int ocol = nblk*128 + wc + j*16 + (lane&15);
        #pragma unroll
        for (int r=0;r<4;r++){
          int off = ((lane>>4)<<2) + r;
          float val = acc[i][j][r] + shift_s[wr + i*16 + off];
          if (rem < 64){
            qk32[((size_t)(b*8+hh)*64 + rem + off)*4096 + ocol] = val;
          } else {
            unsigned short h2, l2; split2(val, h2, l2);
            size_t vidx = ((size_t)(b*8+hh)*32 + (rem-64) + off)*4096 + ocol;
            vhp[vidx] = h2; vlp[vidx] = l2;
          }
        }
      }
    }
  }
}

// ---------------- repack q/k: [bh][64][4096] f32 -> qt/kt [(ba*8+h)][1024][32] packed u32 ----------------
__global__ __launch_bounds__(256)
void repack_qk(const float* __restrict__ qk32, uint32_t* __restrict__ qt, uint32_t* __restrict__ kt)
{
  const int t = threadIdx.x;
  const int nch  = blockIdx.x;   // 0..31: 128-n chunk
  const int type = blockIdx.y;   // 0 q, 1 k
  const int bh   = blockIdx.z;   // 0..15
  __shared__ __align__(16) float tile[32][132];
  const float* src = qk32 + ((size_t)bh*64 + type*32)*4096 + nch*128;
  {
    int d = t>>3, m16 = (t&7)*16;
    const float* sp = src + (size_t)d*4096 + m16;
    *(f32x4*)&tile[d][m16]    = *(const f32x4*)(sp);
    *(f32x4*)&tile[d][m16+4]  = *(const f32x4*)(sp+4);
    *(f32x4*)&tile[d][m16+8]  = *(const f32x4*)(sp+8);
    *(f32x4*)&tile[d][m16+12] = *(const f32x4*)(sp+12);
  }
  __syncthreads();
  {
    int m = t>>1, dh = (t&1)*16;
    int b = bh>>3, h = bh&7;
    int n = nch*128 + m;
    int area = n>>10, mm = n&1023;
    uint32_t* dst = (type ? kt : qt) + ((size_t)((b*4+area)*8 + h)*1024 + mm)*32 + dh;
    uint32_t w[16];
    #pragma unroll
    for (int kk=0; kk<16; kk++){
      unsigned short hh, ll; split2(tile[dh+kk][m], hh, ll);
      w[kk] = ((uint32_t)hh<<16) | ll;
    }
    #pragma unroll
    for (int q4=0;q4<4;q4++){
      uint4 o; o.x=w[q4*4]; o.y=w[q4*4+1]; o.z=w[q4*4+2]; o.w=w[q4*4+3];
      *(uint4*)(dst + q4*4) = o;
    }
  }
}

// ---------------- LDS-free flash attention ----------------
// qt/kt: [(ba*8+h)][m 1024][d 32] packed u32 (hi/lo bf16); vh: [b*8+h][d 32][n 4096] bf16
// writes obuf[b][h*32+d][n]
__global__ __launch_bounds__(256)
void attn_kernel(const uint32_t* __restrict__ qt, const uint32_t* __restrict__ kt,
                 const uint16_t* __restrict__ vh, float* __restrict__ obuf)
{
  const int t = threadIdx.x, lane = t & 63, wid = t >> 6;
  const int g = lane >> 4, li = lane & 15;
  const int nblk = blockIdx.x;   // 0..7
  const int h    = blockIdx.y;   // 0..7
  const int ba   = blockIdx.z;   // 0..7
  const int b = ba >> 2, area = ba & 3;

  __shared__ __align__(16) unsigned short pt[4][32][72];   // per-wave P^T [n][m]

  const size_t qkrow = ((size_t)ba*8 + h)*1024;
  const int nw = nblk*128 + wid*32;

  // Q fragments (once)
  bf16x8 qh[2], ql[2];
  #pragma unroll
  for (int nt=0; nt<2; nt++){
    const uint32_t* qp = qt + (qkrow + nw + nt*16 + li)*32 + g*8;
    uint4 a = *(const uint4*)qp;
    uint4 c = *(const uint4*)(qp+4);
    unpack8(a, c, qh[nt], ql[nt]);
  }

  const uint32_t* kb = kt + qkrow*32;
  const uint16_t* vb = vh + ((size_t)(b*8+h)*32)*4096 + area*1024;

  float mrun[2] = {-1e30f, -1e30f};
  float srun[2] = {0.f, 0.f};
  f32x4 oacc[2][2];
  #pragma unroll
  for (int dt=0;dt<2;dt++)
    #pragma unroll
    for (int nt=0;nt<2;nt++){ f32x4 z = {0.f,0.f,0.f,0.f}; oacc[dt][nt] = z; }

  // prefetch K for iter 0
  uint4 kp[8];
  #pragma unroll
  for (int mt=0;mt<4;mt++){
    const uint32_t* p = kb + (size_t)(mt*16 + li)*32 + g*8;
    kp[mt*2]   = *(const uint4*)p;
    kp[mt*2+1] = *(const uint4*)(p+4);
  }

  for (int m0 = 0; m0 < 1024; m0 += 64){
    // V fragments for this iter (bf16-hi plane, direct)
    bf16x8 vf[2][2];
    #pragma unroll
    for (int dt=0;dt<2;dt++)
      #pragma unroll
      for (int ks=0;ks<2;ks++)
        vf[dt][ks] = *(const bf16x8*)(vb + (size_t)(dt*16+li)*4096 + m0 + ks*32 + g*8);

    // unpack current K
    bf16x8 kfh[4], kfl[4];
    #pragma unroll
    for (int mt=0;mt<4;mt++)
      unpack8(kp[mt*2], kp[mt*2+1], kfh[mt], kfl[mt]);

    // prefetch next K
    if (m0 < 960){
      const uint32_t* kb2 = kb + (size_t)(m0+64)*32;
      #pragma unroll
      for (int mt=0;mt<4;mt++){
        const uint32_t* p = kb2 + (size_t)(mt*16 + li)*32 + g*8;
        kp[mt*2]   = *(const uint4*)p;
        kp[mt*2+1] = *(const uint4*)(p+4);
      }
    }

    // S^T = K Q^T (3-term split, log2 domain)
    f32x4 s[4][2];
    #pragma unroll
    for (int mt=0;mt<4;mt++)
      #pragma unroll
      for (int nt=0;nt<2;nt++){
        f32x4 z = {0.f,0.f,0.f,0.f};
        z = mfma16(kfh[mt], qh[nt], z);
        z = mfma16(kfl[mt], qh[nt], z);
        z = mfma16(kfh[mt], ql[nt], z);
        s[mt][nt] = z;
      }

    // online softmax (per lane: 16 m-values per nt, + 2 shfl across groups)
    #pragma unroll
    for (int nt=0; nt<2; nt++){
      f32x4 m01 = vmax4(s[0][nt], s[1][nt]);
      f32x4 m23 = vmax4(s[2][nt], s[3][nt]);
      f32x4 mm4 = vmax4(m01, m23);
      float mx = fmaxf(fmaxf(mm4[0], mm4[1]), fmaxf(mm4[2], mm4[3]));
      mx = fmaxf(mx, __shfl_xor(mx, 16, 64));
      mx = fmaxf(mx, __shfl_xor(mx, 32, 64));
      float mnew = fmaxf(mrun[nt], mx);
      float corr = __builtin_exp2f(mrun[nt] - mnew);
      mrun[nt] = mnew;
      f32x4 sum4 = {0.f,0.f,0.f,0.f};
      #pragma unroll
      for (int mt=0; mt<4; mt++){
        f32x4 p;
        #pragma unroll
        for (int r=0;r<4;r++) p[r] = __builtin_exp2f(s[mt][nt][r] - mnew);
        sum4 += p;
        uint32_t pk01, pk23;
        asm("v_cvt_pk_bf16_f32 %0, %1, %2" : "=v"(pk01) : "v"(p[0]), "v"(p[1]));
        asm("v_cvt_pk_bf16_f32 %0, %1, %2" : "=v"(pk23) : "v"(p[2]), "v"(p[3]));
        uint2 u; u.x = pk01; u.y = pk23;
        *(uint2*)&pt[wid][nt*16+li][mt*16 + g*4] = u;
      }
      float sm = sum4[0]+sum4[1]+sum4[2]+sum4[3];
      sm += __shfl_xor(sm, 16, 64);
      sm += __shfl_xor(sm, 32, 64);
      srun[nt] = srun[nt]*corr + sm;
      #pragma unroll
      for (int dt=0;dt<2;dt++)
        #pragma unroll
        for (int r=0;r<4;r++) oacc[dt][nt][r] *= corr;
    }

    // O^T += V * P^T  (per-wave private LDS, no barrier needed)
    #pragma unroll
    for (int ks=0; ks<2; ks++)
      #pragma unroll
      for (int nt=0; nt<2; nt++){
        bf16x8 pf = *(const bf16x8*)&pt[wid][nt*16+li][ks*32 + g*8];
        #pragma unroll
        for (int dt=0; dt<2; dt++)
          oacc[dt][nt] = mfma16(vf[dt][ks], pf, oacc[dt][nt]);
      }
  }

  // epilogue
  #pragma unroll
  for (int nt=0;nt<2;nt++){
    float inv = 1.0f / srun[nt];
    #pragma unroll
    for (int dt=0;dt<2;dt++){
      size_t base = ((size_t)b*256 + h*32 + dt*16 + g*4)*4096 + (size_t)(area*1024 + nw + nt*16 + li);
      #pragma unroll
      for (int r=0;r<4;r++)
        obuf[base + (size_t)r*4096] = oacc[dt][nt][r]*inv;
    }
  }
}

// ---------------- depthwise 7x7 conv + BN, accumulate into obuf ----------------
__global__ __launch_bounds__(256)
void dwconv_bn_add(const uint16_t* __restrict__ vhp, const uint16_t* __restrict__ vlp,
                   const float* __restrict__ wpe,
                   const float* __restrict__ gg, const float* __restrict__ bb,
                   const float* __restrict__ bm, const float* __restrict__ bv,
                   float* __restrict__ obuf)
{
  const int t = threadIdx.x;
  const int c = blockIdx.x;
  const int b = blockIdx.y;
  const size_t srow = ((size_t)(b*8 + (c>>5))*32 + (c&31))*4096;
  const uint16_t* sh_ = vhp + srow;
  const uint16_t* sl_ = vlp + srow;
  __shared__ float tile[70*70];
  for (int idx = t; idx < 4900; idx += 256){
    int y = idx/70 - 3, x = idx%70 - 3;
    float v = 0.f;
    if ((unsigned)y < 64u && (unsigned)x < 64u){
      int o = y*64 + x;
      v = bf2f(sh_[o]) + bf2f(sl_[o]);
    }
    tile[idx] = v;
  }
  float wreg[49];
  #pragma unroll
  for (int i=0;i<49;i++) wreg[i] = wpe[c*49 + i];
  float sc = gg[c]*rsqrtf(bv[c]+EPSV);
  float sb = bb[c] - bm[c]*sc;
  __syncthreads();
  float* dst = obuf + ((size_t)b*256 + c)*4096;
  #pragma unroll
  for (int p=0;p<16;p++){
    int pix = t + p*256;
    int y = pix >> 6, x = pix & 63;
    float acc = 0.f;
    #pragma unroll
    for (int ky=0;ky<7;ky++)
      #pragma unroll
      for (int kx=0;kx<7;kx++)
        acc += tile[(y+ky)*70 + x + kx] * wreg[ky*7+kx];
    dst[pix] += acc*sc + sb;
  }
}

extern "C" void kernel_launch(void* const* d_in, const int* in_sizes, int n_in,
                              void* d_out, int out_size, void* d_ws, size_t ws_size,
                              hipStream_t stream) {
  const float* x       = (const float*)d_in[0];
  const float* w_qkv   = (const float*)d_in[1];
  const float* g_qkv   = (const float*)d_in[2];
  const float* b_qkv   = (const float*)d_in[3];
  const float* m_qkv   = (const float*)d_in[4];
  const float* var_qkv = (const float*)d_in[5];
  const float* w_pe    = (const float*)d_in[6];
  const float* g_pe    = (const float*)d_in[7];
  const float* b_pe    = (const float*)d_in[8];
  const float* m_pe    = (const float*)d_in[9];
  const float* var_pe  = (const float*)d_in[10];
  const float* w_proj  = (const float*)d_in[11];
  const float* g_proj  = (const float*)d_in[12];
  const float* b_proj  = (const float*)d_in[13];
  const float* m_proj  = (const float*)d_in[14];
  const float* var_proj= (const float*)d_in[15];

  char* wsb = (char*)d_ws;
  float*     qk32 = (float*)wsb;                          // 16 MiB  [bh][64][4096]
  uint16_t*  vhp  = (uint16_t*)(wsb + 16777216);          // 4 MiB
  uint16_t*  vlp  = (uint16_t*)(wsb + 20971520);          // 4 MiB
  uint32_t*  qtp  = (uint32_t*)(wsb + 25165824);          // 8 MiB
  uint32_t*  ktp  = (uint32_t*)(wsb + 33554432);          // 8 MiB  (total 40 MiB)
  float*     obuf = (float*)wsb;                          // aliases qk32 (dead after repack)
  float*     out  = (float*)d_out;

  gemm_bn_kernel<<<dim3(32,6,2), 256, 0, stream>>>(w_qkv, x, nullptr, qk32, vhp, vlp,
      g_qkv, b_qkv, m_qkv, var_qkv, 768, 1);
  repack_qk<<<dim3(32,2,16), 256, 0, stream>>>(qk32, qtp, ktp);
  attn_kernel<<<dim3(8,8,8), 256, 0, stream>>>(qtp, ktp, vhp, obuf);
  dwconv_bn_add<<<dim3(256,2), 256, 0, stream>>>(vhp, vlp, w_pe,
      g_pe, b_pe, m_pe, var_pe, obuf);
  gemm_bn_kernel<<<dim3(32,2,2), 256, 0, stream>>>(w_proj, obuf, out, nullptr, nullptr, nullptr,
      g_proj, b_proj, m_proj, var_proj, 256, 0);
}